// Round 4
// baseline (42.826 us; speedup 1.0000x reference)
//
#include <hip/hip_runtime.h>

#define DISP_RANGE 10
#define OUT_D 21
#define B_ 8
#define A_ 9
#define D_ 128
#define HW_ 4096   // 64*64

// cost[b,0,a,k,h,w] = wt_k * sum_{dd in [START0+s_k, START0+e_k)} uh[b,a, dd-32+h, h, w]  (0 if row OOB)
// cost[b,1,a,k,h,w] = wt_k * sum_{dd in [START0+s_k, START0+e_k)} vw[b,a, dd-32+w, h, w]  (0 if row OOB)
//
// 512 threads / 8 waves, wave-specialized:
//   waves 0-3: uh path (k-group = wid&3), pure global reads, compute+store
//              BEFORE the barrier -> overlaps the vw staging drain.
//   waves 4-7: issue async global_load_lds staging of vw rows, then after the
//              barrier compute the vw path from LDS (diagonal read, stride-65
//              words -> bank-conflict-free).
// Block-uniform switch on a -> AD template keeps all window bounds constexpr
// (full unroll, streaming loads).

template<int AD, int WID>
__device__ __forceinline__ void compute_uh(
    const float* __restrict__ uh_slice,   // uh + plane + h*64
    float* __restrict__ out0,             // out + base(n=0) + w
    int h, int w)
{
    constexpr int L      = 2 * DISP_RANGE * AD + 1;
    constexpr int START0 = (D_ / 2) - DISP_RANGE * AD;
    constexpr int K0     = (WID == 0) ? 0 : (6 + 5 * (WID - 1));   // 0,6,11,16
    constexpr int K1     = K0 + ((WID == 0) ? 6 : 5);
    constexpr int NK     = K1 - K0;
    constexpr int S0     = (K0 * L) / OUT_D;
    constexpr int E1     = (K1 * L + OUT_D - 1) / OUT_D;

    float acc[NK];
#pragma unroll
    for (int i = 0; i < NK; ++i) acc[i] = 0.0f;

#pragma unroll
    for (int dd = START0 + S0; dd < START0 + E1; ++dd) {
        const int  row  = dd - 32 + h;
        const bool ok   = (row >= 0) && (row < D_);
        const int  rowc = row < 0 ? 0 : (row > D_ - 1 ? D_ - 1 : row);
        float v = uh_slice[(size_t)rowc * HW_ + (size_t)w];
        v = ok ? v : 0.0f;
#pragma unroll
        for (int k = K0; k < K1; ++k) {
            if (dd >= START0 + (k * L) / OUT_D &&
                dd <  START0 + ((k + 1) * L + OUT_D - 1) / OUT_D)
                acc[k - K0] += v;
        }
    }

#pragma unroll
    for (int k = K0; k < K1; ++k) {
        const int   s  = (k * L) / OUT_D;
        const int   e  = ((k + 1) * L + OUT_D - 1) / OUT_D;
        const float wt = 1.0f / (float)(e - s);
        out0[(size_t)k * HW_] = acc[k - K0] * wt;
    }
}

template<int AD, int WID>
__device__ __forceinline__ void compute_vw(
    const float* lds,                     // staged vw rows [LO,HI)
    float* __restrict__ out1,             // out + base(n=1) + w
    int w)
{
    constexpr int L      = 2 * DISP_RANGE * AD + 1;
    constexpr int START0 = (D_ / 2) - DISP_RANGE * AD;
    constexpr int LO     = (START0 - 32 < 0) ? 0 : (START0 - 32);
    constexpr int HI     = (START0 + L + 31 > D_) ? D_ : (START0 + L + 31);
    constexpr int K0     = (WID == 0) ? 0 : (6 + 5 * (WID - 1));
    constexpr int K1     = K0 + ((WID == 0) ? 6 : 5);
    constexpr int NK     = K1 - K0;
    constexpr int S0     = (K0 * L) / OUT_D;
    constexpr int E1     = (K1 * L + OUT_D - 1) / OUT_D;

    float acc[NK];
#pragma unroll
    for (int i = 0; i < NK; ++i) acc[i] = 0.0f;

#pragma unroll
    for (int dd = START0 + S0; dd < START0 + E1; ++dd) {
        const int  rv  = dd - 32 + w;
        const bool ok  = (rv >= LO) && (rv < HI);
        const int  rvc = rv < LO ? LO : (rv > HI - 1 ? HI - 1 : rv);
        float v = lds[(rvc - LO) * 64 + w];
        v = ok ? v : 0.0f;
#pragma unroll
        for (int k = K0; k < K1; ++k) {
            if (dd >= START0 + (k * L) / OUT_D &&
                dd <  START0 + ((k + 1) * L + OUT_D - 1) / OUT_D)
                acc[k - K0] += v;
        }
    }

#pragma unroll
    for (int k = K0; k < K1; ++k) {
        const int   s  = (k * L) / OUT_D;
        const int   e  = ((k + 1) * L + OUT_D - 1) / OUT_D;
        const float wt = 1.0f / (float)(e - s);
        out1[(size_t)k * HW_] = acc[k - K0] * wt;
    }
}

template<int AD>
__device__ __forceinline__ void run_block(
    const float* __restrict__ uh,
    const float* __restrict__ vw,
    float* __restrict__ out,
    float* lds,
    int b, int a, int h, int t)
{
    constexpr int L      = 2 * DISP_RANGE * AD + 1;
    constexpr int START0 = (D_ / 2) - DISP_RANGE * AD;
    constexpr int LO     = (START0 - 32 < 0) ? 0 : (START0 - 32);
    constexpr int HI     = (START0 + L + 31 > D_) ? D_ : (START0 + L + 31);
    constexpr int NROWS  = HI - LO;        // 84 / 104 / 124 / 128 (all %4==0)
    constexpr int NCH    = NROWS / 4;      // 4-row, 1KB chunks

    const int lane = t & 63;
    const int w    = lane;
    const int wid  = t >> 6;               // 0..7

    const size_t plane = (size_t)(b * A_ + a) * D_ * HW_;
    const float* uh_slice = uh + plane + (size_t)h * 64;
    const float* vw_slice = vw + plane + (size_t)h * 64;

    // ---- waves 4-7: issue async staging of vw rows [LO,HI) into LDS ----
    // chunk c = rows [LO+4c, LO+4c+4); lane l covers row +(l>>4), f4 col (l&15).
    if (wid >= 4) {
        const int sg = wid - 4;
#pragma unroll
        for (int c = 0; c < NCH; ++c) {
            if ((c & 3) == sg) {
                const float* src = vw_slice
                    + (size_t)(LO + c * 4 + (lane >> 4)) * HW_
                    + (size_t)((lane & 15) * 4);
                __builtin_amdgcn_global_load_lds(
                    (const __attribute__((address_space(1))) void*)src,
                    (__attribute__((address_space(3))) void*)&lds[c * 256],
                    16, 0, 0);
            }
        }
    }

    const size_t out_b0 = ((size_t)(b * 2) * A_ + a) * OUT_D * HW_
                        + (size_t)h * 64 + (size_t)w;
    const size_t out_b1 = out_b0 + (size_t)A_ * OUT_D * HW_;

    // ---- waves 0-3: full uh path before the barrier (hides staging drain) ----
    if (wid < 4) {
        float* out0 = out + out_b0;
        switch (wid) {
            case 0: compute_uh<AD, 0>(uh_slice, out0, h, w); break;
            case 1: compute_uh<AD, 1>(uh_slice, out0, h, w); break;
            case 2: compute_uh<AD, 2>(uh_slice, out0, h, w); break;
            default: compute_uh<AD, 3>(uh_slice, out0, h, w); break;
        }
    }

    __syncthreads();

    // ---- waves 4-7: vw path from LDS ----
    if (wid >= 4) {
        float* out1 = out + out_b1;
        switch (wid - 4) {
            case 0: compute_vw<AD, 0>(lds, out1, w); break;
            case 1: compute_vw<AD, 1>(lds, out1, w); break;
            case 2: compute_vw<AD, 2>(lds, out1, w); break;
            default: compute_vw<AD, 3>(lds, out1, w); break;
        }
    }
}

__global__ __launch_bounds__(512, 8) void cost_volume_kernel(
    const float* __restrict__ uh,
    const float* __restrict__ vw,
    float* __restrict__ out)
{
    __shared__ float lds[D_ * 64];   // 32 KiB (max case AD=4)

    const int h = blockIdx.x;
    const int a = blockIdx.y;
    const int b = blockIdx.z;
    const int t = (int)threadIdx.x;

    // AD = max(|a-4|,1), block-uniform branch into constexpr path
    switch (a) {
        case 3: case 4: case 5:
            run_block<1>(uh, vw, out, lds, b, a, h, t); break;
        case 2: case 6:
            run_block<2>(uh, vw, out, lds, b, a, h, t); break;
        case 1: case 7:
            run_block<3>(uh, vw, out, lds, b, a, h, t); break;
        default:   // 0, 8
            run_block<4>(uh, vw, out, lds, b, a, h, t); break;
    }
}

extern "C" void kernel_launch(void* const* d_in, const int* in_sizes, int n_in,
                              void* d_out, int out_size, void* d_ws, size_t ws_size,
                              hipStream_t stream) {
    const float* uh = (const float*)d_in[0];   // [8,9,128,64,64] f32
    const float* vw = (const float*)d_in[1];   // [8,9,128,64,64] f32
    float* out = (float*)d_out;                // [8,2,9,21,64,64] f32

    dim3 grid(64, A_, B_);   // (h, a, b) = 4608 blocks
    dim3 block(512);
    cost_volume_kernel<<<grid, block, 0, stream>>>(uh, vw, out);
}